// Round 1
// baseline (545.356 us; speedup 1.0000x reference)
//
#include <hip/hip_runtime.h>

// SSN superpixel EM, MI355X. B=4, H=W=256, C=20, KG=16 (K=256), CELL=16, 10 EM iters.
// Exploits 9-neighborhood sparsity: posteriors are exactly 0 outside it (exp underflow).

#define NBATCH 4
#define WIMG   256
#define NC     20      // feature channels
#define NCS    21      // channels + colsum slot
#define NKG    16
#define NK     256
#define NPIX   65536
#define CELLSZ 16
#define LDST   260     // LDS row stride (floats), 16B-aligned rows

__device__ __forceinline__ float dot4f(const float4 a, const float4 b) {
    return fmaf(a.x, b.x, fmaf(a.y, b.y, fmaf(a.z, b.z, a.w * b.w)));
}

__device__ __forceinline__ void load_feat(const float* __restrict__ feat, int b, int n, float f[NC]) {
    const float4* fp = (const float4*)(feat + ((size_t)b * NPIX + n) * NC);  // 80B/pixel, 16B aligned
    #pragma unroll
    for (int i = 0; i < 5; ++i) {
        float4 v = fp[i];
        f[4 * i + 0] = v.x; f[4 * i + 1] = v.y; f[4 * i + 2] = v.z; f[4 * i + 3] = v.w;
    }
}

// E-step for one pixel against its 9 neighbor superpixels.
// Sprev layout: [b][k][21], slot 20 = colsum. mean = S/col. feat_sq cancels in softmax.
__device__ __forceinline__ void e_step(const float* f, int b, int cy, int cx,
                                       const float* __restrict__ Sprev, float p[9]) {
    float a[9];
    float amax = -1e30f;
    #pragma unroll
    for (int dy = -1; dy <= 1; ++dy) {
        #pragma unroll
        for (int dx = -1; dx <= 1; ++dx) {
            int j = (dy + 1) * 3 + (dx + 1);
            int ky = cy + dy, kx = cx + dx;
            if (ky >= 0 && ky < NKG && kx >= 0 && kx < NKG) {   // wave-uniform branch
                const float* sp = Sprev + ((size_t)(b * NK + ky * NKG + kx)) * NCS;  // uniform -> s_load
                float dots = 0.f, ssq = 0.f;
                #pragma unroll
                for (int c = 0; c < NC; ++c) {
                    float sv = sp[c];
                    dots = fmaf(f[c], sv, dots);
                    ssq  = fmaf(sv, sv, ssq);
                }
                float col = fmaxf(sp[NC], 1e-12f);
                float r = 1.0f / col;
                // -dist + feat_sq = 2*f.mean - ||mean||^2
                a[j] = 2.0f * r * dots - (r * r) * ssq;
                amax = fmaxf(amax, a[j]);
            } else {
                a[j] = -1e30f;
            }
        }
    }
    float esum = 0.f;
    #pragma unroll
    for (int j = 0; j < 9; ++j) {
        float e = (a[j] > -1e29f) ? __expf(a[j] - amax) : 0.0f;
        p[j] = e;
        esum += e;
    }
    float inv = 1.0f / esum;
    #pragma unroll
    for (int j = 0; j < 9; ++j) p[j] *= inv;
}

// Initial mean: per-cell feature mean (col = 256). Writes S0, zeros S1.
__global__ __launch_bounds__(256, 4) void k_init(const float* __restrict__ feat,
                                                 float* __restrict__ S0,
                                                 float* __restrict__ S1) {
    __shared__ float fT[NC * LDST];
    int blk = blockIdx.x;
    int b = blk >> 8, k0 = blk & 255;
    int cy = k0 >> 4, cx = k0 & 15;
    int t = threadIdx.x;
    int ly = t >> 4, lx = t & 15;
    int n = (cy * CELLSZ + ly) * WIMG + cx * CELLSZ + lx;
    float f[NC];
    load_feat(feat, b, n, f);
    #pragma unroll
    for (int c = 0; c < NC; ++c) fT[c * LDST + t] = f[c];
    __syncthreads();
    if (t < NCS) {
        float s;
        if (t == NC) {
            s = 256.0f;
        } else {
            s = 0.f;
            const float4* row = (const float4*)&fT[t * LDST];
            #pragma unroll 4
            for (int i = 0; i < 64; ++i) { float4 v = row[i]; s += v.x + v.y + v.z + v.w; }
        }
        size_t off = ((size_t)(b * NK + k0)) * NCS + t;
        S0[off] = s;
        S1[off] = 0.0f;
    }
}

// One fused EM iteration: E-step (9-sparse softmax) + M-step accumulation.
// Reads Sprev, atomically accumulates into Snext (pre-zeroed), zeros Szero for next round.
__global__ __launch_bounds__(256, 4) void k_em(const float* __restrict__ feat,
                                               const float* __restrict__ Sprev,
                                               float* __restrict__ Snext,
                                               float* __restrict__ Szero) {
    __shared__ float fT[NCS * LDST];     // [c][n], row 20 = ones (colsum)
    __shared__ float pT[9 * LDST];       // [j][n]
    __shared__ float part[21 * 8 * 9];   // [tile][kid][3x3]
    int blk = blockIdx.x;
    int b = blk >> 8, k0 = blk & 255;
    int cy = k0 >> 4, cx = k0 & 15;
    int t = threadIdx.x;
    int ly = t >> 4, lx = t & 15;
    int n = (cy * CELLSZ + ly) * WIMG + cx * CELLSZ + lx;
    float f[NC];
    load_feat(feat, b, n, f);
    #pragma unroll
    for (int c = 0; c < NC; ++c) fT[c * LDST + t] = f[c];
    fT[NC * LDST + t] = 1.0f;
    float p[9];
    e_step(f, b, cy, cx, Sprev, p);
    #pragma unroll
    for (int j = 0; j < 9; ++j) pT[j * LDST + t] = p[j];
    __syncthreads();

    // Tiled [9x256]x[256x21] reduction: 21 (3j x 3c) tiles x 8 K-splits = 168 threads.
    if (t < 168) {
        int tile = t >> 3, kid = t & 7;
        int j0 = (tile / 7) * 3, c0 = (tile % 7) * 3;
        float acc[3][3] = {};
        #pragma unroll
        for (int ch = 0; ch < 8; ++ch) {
            int nb = kid * 32 + (((ch + kid) & 7) << 2);  // XOR-swizzle: kid*32 alone aliases banks
            float4 pv[3], fv[3];
            #pragma unroll
            for (int jj = 0; jj < 3; ++jj) pv[jj] = *(const float4*)&pT[(j0 + jj) * LDST + nb];
            #pragma unroll
            for (int cc = 0; cc < 3; ++cc) fv[cc] = *(const float4*)&fT[(c0 + cc) * LDST + nb];
            #pragma unroll
            for (int jj = 0; jj < 3; ++jj)
                #pragma unroll
                for (int cc = 0; cc < 3; ++cc)
                    acc[jj][cc] += dot4f(pv[jj], fv[cc]);
        }
        #pragma unroll
        for (int jj = 0; jj < 3; ++jj)
            #pragma unroll
            for (int cc = 0; cc < 3; ++cc)
                part[tile * 72 + kid * 9 + jj * 3 + cc] = acc[jj][cc];
    }
    __syncthreads();
    if (t < 189) {
        int j = t / 21, c = t % 21;
        int tile = (j / 3) * 7 + (c / 3);
        int elem = (j % 3) * 3 + (c % 3);
        float s = 0.f;
        #pragma unroll
        for (int kid = 0; kid < 8; ++kid) s += part[tile * 72 + kid * 9 + elem];
        int ky = cy + (j / 3) - 1, kx = cx + (j % 3) - 1;
        if (ky >= 0 && ky < NKG && kx >= 0 && kx < NKG)
            atomicAdd(&Snext[((size_t)(b * NK + ky * NKG + kx)) * NCS + c], s);
    }
    // Zero the third buffer (accumulation target two iterations out). Disjoint from Sprev/Snext.
    if (t < NCS) Szero[((size_t)(b * NK + k0)) * NCS + t] = 0.0f;
}

// Final E-step + dense [B,N,K] output write (zeros for non-neighbors), coalesced float4 rows.
__global__ __launch_bounds__(256, 4) void k_final(const float* __restrict__ feat,
                                                  const float* __restrict__ Sprev,
                                                  float* __restrict__ out) {
    __shared__ float pT[9 * LDST];
    int blk = blockIdx.x;
    int b = blk >> 8, k0 = blk & 255;
    int cy = k0 >> 4, cx = k0 & 15;
    int t = threadIdx.x;
    int ly = t >> 4, lx = t & 15;
    int n = (cy * CELLSZ + ly) * WIMG + cx * CELLSZ + lx;
    float f[NC];
    load_feat(feat, b, n, f);
    float p[9];
    e_step(f, b, cy, cx, Sprev, p);
    #pragma unroll
    for (int j = 0; j < 9; ++j) pT[j * LDST + t] = p[j];
    __syncthreads();

    // Each wave writes full 256-float K-rows for 64 pixels: lane covers k = 4*ln .. 4*ln+3.
    int wv = t >> 6, ln = t & 63;
    int j4[4];
    #pragma unroll
    for (int q = 0; q < 4; ++q) {
        int k = 4 * ln + q;
        int ky = k >> 4, kx = k & 15;
        int dy = ky - cy, dx = kx - cx;
        j4[q] = (dy >= -1 && dy <= 1 && dx >= -1 && dx <= 1) ? (dy + 1) * 3 + (dx + 1) : -1;
    }
    for (int i = 0; i < 64; ++i) {
        int pix = wv * 64 + i;
        int py = pix >> 4, px = pix & 15;
        int np = (cy * CELLSZ + py) * WIMG + cx * CELLSZ + px;
        float4 o;
        o.x = (j4[0] >= 0) ? pT[j4[0] * LDST + pix] : 0.0f;
        o.y = (j4[1] >= 0) ? pT[j4[1] * LDST + pix] : 0.0f;
        o.z = (j4[2] >= 0) ? pT[j4[2] * LDST + pix] : 0.0f;
        o.w = (j4[3] >= 0) ? pT[j4[3] * LDST + pix] : 0.0f;
        size_t rowoff = ((size_t)(b * NPIX + np)) * (size_t)NK;
        *(float4*)(out + rowoff + 4 * ln) = o;
    }
}

extern "C" void kernel_launch(void* const* d_in, const int* in_sizes, int n_in,
                              void* d_out, int out_size, void* d_ws, size_t ws_size,
                              hipStream_t stream) {
    (void)in_sizes; (void)n_in; (void)out_size; (void)ws_size;
    const float* feat = (const float*)d_in[0];
    // d_in[1..4] (valid_spixel, adjust_dist, spixel_init, iter_EM) are implied by geometry.
    float* out = (float*)d_out;
    const size_t SB = (size_t)NBATCH * NK * NCS;  // 21504 floats per buffer
    float* bufs[3] = { (float*)d_ws, (float*)d_ws + SB, (float*)d_ws + 2 * SB };

    dim3 grid(NBATCH * NK), block(256);
    k_init<<<grid, block, 0, stream>>>(feat, bufs[0], bufs[1]);
    for (int i = 1; i <= 9; ++i) {
        k_em<<<grid, block, 0, stream>>>(feat, bufs[(i - 1) % 3], bufs[i % 3], bufs[(i + 1) % 3]);
    }
    k_final<<<grid, block, 0, stream>>>(feat, bufs[0], out);  // E9 accumulated into bufs[0]
}